// Round 10
// baseline (115.608 us; speedup 1.0000x reference)
//
#include <hip/hip_runtime.h>
#include <hip/hip_cooperative_groups.h>

namespace cg = cooperative_groups;

#define Gc 8
#define Dc 32
#define Hc 128
#define Wc 160
#define HW (Hc * Wc)         // 20480
#define DHW (Dc * HW)        // 655360
#define NTHREADS 327680      // total quads (= threads) for both phases
#define NBLOCKS 1280         // 327680 / 256, exact

// ---------------------------------------------------------------------------
// Shared device bodies (used by both the cooperative kernel and the
// two-launch fallback). Straight-line, interleaved-acc structure proven in
// rounds 6-9: no loops in the MLP body (loops -> compiler pipelining ->
// 208+ VGPR / spill), no register caps (caps 84/64/128 all spilled).
// ---------------------------------------------------------------------------
__device__ __forceinline__ void stage_weights(
    float* smw, int tid,
    const float* w0, const float* s0, const float* b0,
    const float* w1, const float* s1, const float* b1,
    const float* wsim, const float* bsim)
{
    for (int i = tid; i < 289; i += 256) {
        float v;
        if (i < 128)      v = w0[i] * s0[i >> 3];                 // w0f[o][g]
        else if (i < 144) v = b0[i - 128];
        else if (i < 272) v = w1[i - 144] * s1[(i - 144) >> 4];   // w1f[c][o]
        else if (i < 280) v = b1[i - 272];
        else if (i < 288) v = wsim[i - 280];
        else              v = bsim[0];
        smw[i] = v;
    }
}

__device__ __forceinline__ void mlp_body(
    int t, const float* __restrict__ x1, const float* smw,
    float* __restrict__ sim)
{
    const float* sw0 = smw;
    const float* sb0 = smw + 128;
    const float* sw1 = smw + 144;
    const float* sb1 = smw + 272;
    const float* sws = smw + 280;
    const float  sbs = smw[288];

    const int p   = t << 2;                   // base point over (b,d,h,w)
    const int b   = p / DHW;
    const int dhw = p - b * DHW;
    const float* xb = x1 + (size_t)b * (Gc * DHW) + dhw;

    float4 xv[Gc];
#pragma unroll
    for (int g = 0; g < Gc; ++g)
        xv[g] = *reinterpret_cast<const float4*>(xb + g * DHW);

    float4 acc1[8];
#pragma unroll
    for (int c = 0; c < 8; ++c) {
        const float bb = sb1[c];
        acc1[c].x = bb; acc1[c].y = bb; acc1[c].z = bb; acc1[c].w = bb;
    }

#pragma unroll
    for (int o = 0; o < 16; ++o) {
        float ax = sb0[o], ay = ax, az = ax, aw = ax;
#pragma unroll
        for (int g = 0; g < Gc; ++g) {
            const float wv = sw0[o * Gc + g];
            ax = fmaf(wv, xv[g].x, ax);
            ay = fmaf(wv, xv[g].y, ay);
            az = fmaf(wv, xv[g].z, az);
            aw = fmaf(wv, xv[g].w, aw);
        }
        ax = fmaxf(ax, 0.f);
        ay = fmaxf(ay, 0.f);
        az = fmaxf(az, 0.f);
        aw = fmaxf(aw, 0.f);
#pragma unroll
        for (int c = 0; c < 8; ++c) {
            const float wv = sw1[c * 16 + o];
            acc1[c].x = fmaf(wv, ax, acc1[c].x);
            acc1[c].y = fmaf(wv, ay, acc1[c].y);
            acc1[c].z = fmaf(wv, az, acc1[c].z);
            acc1[c].w = fmaf(wv, aw, acc1[c].w);
        }
    }

    float sx = sbs, sy = sbs, sz = sbs, sw = sbs;
#pragma unroll
    for (int c = 0; c < 8; ++c) {
        const float ws = sws[c];
        sx = fmaf(ws, fmaxf(acc1[c].x, 0.f), sx);
        sy = fmaf(ws, fmaxf(acc1[c].y, 0.f), sy);
        sz = fmaf(ws, fmaxf(acc1[c].z, 0.f), sz);
        sw = fmaf(ws, fmaxf(acc1[c].w, 0.f), sw);
    }

    float4 r; r.x = sx; r.y = sy; r.z = sz; r.w = sw;
    *reinterpret_cast<float4*>(sim + p) = r;
}

__device__ __forceinline__ void agg_body(
    int l, const float* __restrict__ sim, const float* __restrict__ offset,
    const float* __restrict__ weight, float* __restrict__ out)
{
    const int q  = l % (Wc / 4);
    const int w4 = q * 4;
    int r = l / (Wc / 4);
    const int h = r % Hc;
    r /= Hc;
    const int d = r & 31;
    const int b = r >> 5;                           // 0..1
    const int hw4 = h * Wc + w4;

    const float* offb = offset + (size_t)b * 18 * HW;
    float4 off4[18];
#pragma unroll
    for (int s = 0; s < 18; ++s)
        off4[s] = *reinterpret_cast<const float4*>(offb + s * HW + hw4);
    float4 wt4 = *reinterpret_cast<const float4*>(weight + (size_t)b * HW + hw4);
    wt4.x *= 0.5f; wt4.y *= 0.5f; wt4.z *= 0.5f; wt4.w *= 0.5f;

    int y1[3], y2[3];
#pragma unroll
    for (int iy = 0; iy < 3; ++iy) {
        int a1 = h + (iy - 1) * 2; y1[iy] = a1 < 0 ? -a1 : (a1 >= Hc ? 2 * Hc - 2 - a1 : a1);
        int a2 = h + (iy - 1) * 4; y2[iy] = a2 < 0 ? -a2 : (a2 >= Hc ? 2 * Hc - 2 - a2 : a2);
    }

    const float* sp = sim + (size_t)(b * Dc + d) * HW;
    float ax = 0.f, ay = 0.f, az = 0.f, aw = 0.f;

    if (w4 >= 4 && w4 <= Wc - 8) {
#pragma unroll
        for (int s = 0; s < 9; ++s) {
            const int iy = s / 3, ix = s % 3;
            const float4 cw = *reinterpret_cast<const float4*>(
                sp + y2[iy] * Wc + w4 + (ix - 1) * 4);
            const float* np = sp + y1[iy] * Wc + w4 + (ix - 1) * 2;
            const float2 n0 = *reinterpret_cast<const float2*>(np);
            const float2 n1 = *reinterpret_cast<const float2*>(np + 2);
            const float4 ow = off4[s];
            const float4 on = off4[s + 9];
            ax = fmaf(on.x, n0.x, fmaf(ow.x, cw.x, ax));
            ay = fmaf(on.y, n0.y, fmaf(ow.y, cw.y, ay));
            az = fmaf(on.z, n1.x, fmaf(ow.z, cw.z, az));
            aw = fmaf(on.w, n1.y, fmaf(ow.w, cw.w, aw));
        }
    } else {
        float acc[4] = {0.f, 0.f, 0.f, 0.f};
#pragma unroll
        for (int j = 0; j < 4; ++j) {
            const int w = w4 + j;
            float a = 0.f;
#pragma unroll
            for (int s = 0; s < 9; ++s) {
                const int iy = s / 3, ix = s % 3;
                int x1c = w + (ix - 1) * 2; x1c = x1c < 0 ? -x1c : (x1c >= Wc ? 2 * Wc - 2 - x1c : x1c);
                int x2c = w + (ix - 1) * 4; x2c = x2c < 0 ? -x2c : (x2c >= Wc ? 2 * Wc - 2 - x2c : x2c);
                const float on = j == 0 ? off4[s + 9].x : j == 1 ? off4[s + 9].y : j == 2 ? off4[s + 9].z : off4[s + 9].w;
                const float ow = j == 0 ? off4[s].x     : j == 1 ? off4[s].y     : j == 2 ? off4[s].z     : off4[s].w;
                a = fmaf(on, sp[y1[iy] * Wc + x1c], fmaf(ow, sp[y2[iy] * Wc + x2c], a));
            }
            acc[j] = a;
        }
        ax = acc[0]; ay = acc[1]; az = acc[2]; aw = acc[3];
    }

    float4 o4;
    o4.x = ax * wt4.x;
    o4.y = ay * wt4.y;
    o4.z = az * wt4.z;
    o4.w = aw * wt4.w;
    float* outb = out + (size_t)(b * Dc + d) * HW;
    *reinterpret_cast<float4*>(outb + hw4) = o4;
}

// ---------------------------------------------------------------------------
// Cooperative fused kernel: phase A (MLP) -> grid.sync -> phase B (agg).
// One dispatch instead of two: removes inter-kernel drain + re-dispatch ramp
// + second launch overhead. 1280 blocks = 5 blocks/CU co-resident; each block
// aggs the same linear range it computed (sim taps mostly cache-local).
// grid.sync provides the device-scope fence needed for cross-XCD halo reads.
// ---------------------------------------------------------------------------
__global__ __launch_bounds__(256) void fused_coop(
    const float* __restrict__ x1, const float* __restrict__ offset,
    const float* __restrict__ weight,
    const float* __restrict__ w0, const float* __restrict__ s0, const float* __restrict__ b0,
    const float* __restrict__ w1, const float* __restrict__ s1, const float* __restrict__ b1,
    const float* __restrict__ wsim, const float* __restrict__ bsim,
    float* __restrict__ sim, float* __restrict__ out)
{
    __shared__ float smw[289];
    const int tid = threadIdx.x;
    stage_weights(smw, tid, w0, s0, b0, w1, s1, b1, wsim, bsim);
    __syncthreads();
    const int t = blockIdx.x * 256 + tid;
    mlp_body(t, x1, smw, sim);
    cg::this_grid().sync();
    agg_body(t, sim, offset, weight, out);
}

// ---------------------------------------------------------------------------
// Fallback path: exact round-9 two-kernel pipeline (proven, 115.4 us).
// Used if the coop kernel's VGPR count denies 5 blocks/CU co-residency.
// ---------------------------------------------------------------------------
__global__ __launch_bounds__(256) void mlp_kernel(
    const float* __restrict__ x1,
    const float* __restrict__ w0, const float* __restrict__ s0, const float* __restrict__ b0,
    const float* __restrict__ w1, const float* __restrict__ s1, const float* __restrict__ b1,
    const float* __restrict__ wsim, const float* __restrict__ bsim,
    float* __restrict__ sim)
{
    __shared__ float smw[289];
    const int tid = threadIdx.x;
    stage_weights(smw, tid, w0, s0, b0, w1, s1, b1, wsim, bsim);
    __syncthreads();
    mlp_body(blockIdx.x * 256 + tid, x1, smw, sim);
}

__global__ __launch_bounds__(256) void agg_kernel(
    const float* __restrict__ sim, const float* __restrict__ offset,
    const float* __restrict__ weight, float* __restrict__ out)
{
    agg_body(blockIdx.x * 256 + threadIdx.x, sim, offset, weight, out);
}

extern "C" void kernel_launch(void* const* d_in, const int* in_sizes, int n_in,
                              void* d_out, int out_size, void* d_ws, size_t ws_size,
                              hipStream_t stream)
{
    const float* x1     = (const float*)d_in[0];
    const float* offset = (const float*)d_in[1];
    const float* weight = (const float*)d_in[2];
    const float* w0     = (const float*)d_in[3];
    const float* s0     = (const float*)d_in[4];
    const float* b0     = (const float*)d_in[5];
    const float* w1     = (const float*)d_in[6];
    const float* s1     = (const float*)d_in[7];
    const float* b1     = (const float*)d_in[8];
    const float* wsim   = (const float*)d_in[9];
    const float* bsim   = (const float*)d_in[10];
    float* out = (float*)d_out;
    float* sim = (float*)d_ws;   // B*D*H*W floats = 5.25 MB scratch

    // Decide coop feasibility ONCE via occupancy query (host-only, no stream
    // ops -> graph-capture safe). Need 5 blocks/CU for 1280 co-resident.
    static int coop_ok = -1;
    if (coop_ok < 0) {
        int maxb = 0;
        hipError_t e = hipOccupancyMaxActiveBlocksPerMultiprocessor(
            &maxb, fused_coop, 256, 0);
        coop_ok = (e == hipSuccess && maxb >= 5) ? 1 : 0;
    }

    if (coop_ok) {
        void* args[] = { (void*)&x1, (void*)&offset, (void*)&weight,
                         (void*)&w0, (void*)&s0, (void*)&b0,
                         (void*)&w1, (void*)&s1, (void*)&b1,
                         (void*)&wsim, (void*)&bsim,
                         (void*)&sim, (void*)&out };
        hipLaunchCooperativeKernel((const void*)fused_coop,
                                   dim3(NBLOCKS), dim3(256), args, 0, stream);
    } else {
        mlp_kernel<<<NBLOCKS, 256, 0, stream>>>(x1, w0, s0, b0, w1, s1, b1,
                                                wsim, bsim, sim);
        agg_kernel<<<NBLOCKS, 256, 0, stream>>>(sim, offset, weight, out);
    }
}

// Round 11
// 114.401 us; speedup vs baseline: 1.0106x; 1.0106x over previous
//
#include <hip/hip_runtime.h>

#define Gc 8
#define Dc 32
#define Hc 128
#define Wc 160
#define HW (Hc * Wc)         // 20480
#define DHW (Dc * HW)        // 655360

// ---------------------------------------------------------------------------
// Kernel A: per-point MLP 8 -> 16 -> 8 -> 1 (BN folded into LDS weights).
// One thread = TWO w-points (float2): halves the register footprint of the
// proven straight-line body (xv 16 + acc1 16 + addr ~= 55-65 VGPR) ->
// ~8 waves/SIMD, 2x the latency hiding of the float4 version (~110 VGPR,
// 4 waves/SIMD). Same bytes, same per-pixel VALU; load count doubles but
// TA cycles are unchanged (16 x 512B vs 8 x 1KB per wave).
// STRAIGHT-LINE: no loops in the body (loops -> pipelining -> 208+ VGPR or
// spill, rounds 1-5), no register caps (caps 84/64/128 all spilled).
// ---------------------------------------------------------------------------
__global__ __launch_bounds__(256) void mlp_kernel(
    const float* __restrict__ x1,
    const float* __restrict__ w0, const float* __restrict__ s0, const float* __restrict__ b0,
    const float* __restrict__ w1, const float* __restrict__ s1, const float* __restrict__ b1,
    const float* __restrict__ wsim, const float* __restrict__ bsim,
    float* __restrict__ sim)
{
    __shared__ float smw[289];
    const int tid = threadIdx.x;
    for (int i = tid; i < 289; i += 256) {
        float v;
        if (i < 128)      v = w0[i] * s0[i >> 3];                 // w0f[o][g]
        else if (i < 144) v = b0[i - 128];
        else if (i < 272) v = w1[i - 144] * s1[(i - 144) >> 4];   // w1f[c][o]
        else if (i < 280) v = b1[i - 272];
        else if (i < 288) v = wsim[i - 280];
        else              v = bsim[0];
        smw[i] = v;
    }
    __syncthreads();
    const float* sw0 = smw;
    const float* sb0 = smw + 128;
    const float* sw1 = smw + 144;
    const float* sb1 = smw + 272;
    const float* sws = smw + 280;
    const float  sbs = smw[288];

    const int t   = blockIdx.x * 256 + tid;   // 0 .. 655359 (exact grid)
    const int p   = t << 1;                   // base point over (b,d,h,w)
    const int b   = p / DHW;
    const int dhw = p - b * DHW;
    const float* xb = x1 + (size_t)b * (Gc * DHW) + dhw;

    float2 xv[Gc];
#pragma unroll
    for (int g = 0; g < Gc; ++g)
        xv[g] = *reinterpret_cast<const float2*>(xb + g * DHW);

    // layer-1 accumulators seeded with bias1 (8 x float2 = 16 regs)
    float2 acc1[8];
#pragma unroll
    for (int c = 0; c < 8; ++c) {
        const float bb = sb1[c];
        acc1[c].x = bb; acc1[c].y = bb;
    }

    // layer 0 fused into layer 1: h0[o] consumed immediately (never an array)
#pragma unroll
    for (int o = 0; o < 16; ++o) {
        float ax = sb0[o], ay = ax;
#pragma unroll
        for (int g = 0; g < Gc; ++g) {
            const float wv = sw0[o * Gc + g];
            ax = fmaf(wv, xv[g].x, ax);
            ay = fmaf(wv, xv[g].y, ay);
        }
        ax = fmaxf(ax, 0.f);
        ay = fmaxf(ay, 0.f);
#pragma unroll
        for (int c = 0; c < 8; ++c) {
            const float wv = sw1[c * 16 + o];
            acc1[c].x = fmaf(wv, ax, acc1[c].x);
            acc1[c].y = fmaf(wv, ay, acc1[c].y);
        }
    }

    // sim projection 8 -> 1
    float sx = sbs, sy = sbs;
#pragma unroll
    for (int c = 0; c < 8; ++c) {
        const float ws = sws[c];
        sx = fmaf(ws, fmaxf(acc1[c].x, 0.f), sx);
        sy = fmaf(ws, fmaxf(acc1[c].y, 0.f), sy);
    }

    float2 r; r.x = sx; r.y = sy;
    *reinterpret_cast<float2*>(sim + p) = r;
}

// ---------------------------------------------------------------------------
// Kernel B: UNCHANGED from round 9 (proven 115.4 us path).
// 9-neighbor aggregation, dilations 2 (narrow) & 4 (wide), reflect padding,
// * 0.5 * weight. One thread = one (b,d,h, 4-wide w quad); 327680 quads ->
// grid 1280x256 exact. sim is L2-warm from kernel A.
// ---------------------------------------------------------------------------
__global__ __launch_bounds__(256) void agg_kernel(
    const float* __restrict__ sim, const float* __restrict__ offset,
    const float* __restrict__ weight, float* __restrict__ out)
{
    const int l  = blockIdx.x * 256 + threadIdx.x;  // 0 .. 327679 (exact)
    const int q  = l % (Wc / 4);
    const int w4 = q * 4;
    int r = l / (Wc / 4);
    const int h = r % Hc;
    r /= Hc;
    const int d = r & 31;
    const int b = r >> 5;                           // 0..1
    const int hw4 = h * Wc + w4;

    const float* offb = offset + (size_t)b * 18 * HW;
    float4 off4[18];
#pragma unroll
    for (int s = 0; s < 18; ++s)
        off4[s] = *reinterpret_cast<const float4*>(offb + s * HW + hw4);
    float4 wt4 = *reinterpret_cast<const float4*>(weight + (size_t)b * HW + hw4);
    wt4.x *= 0.5f; wt4.y *= 0.5f; wt4.z *= 0.5f; wt4.w *= 0.5f;

    int y1[3], y2[3];
#pragma unroll
    for (int iy = 0; iy < 3; ++iy) {
        int a1 = h + (iy - 1) * 2; y1[iy] = a1 < 0 ? -a1 : (a1 >= Hc ? 2 * Hc - 2 - a1 : a1);
        int a2 = h + (iy - 1) * 4; y2[iy] = a2 < 0 ? -a2 : (a2 >= Hc ? 2 * Hc - 2 - a2 : a2);
    }

    const float* sp = sim + (size_t)(b * Dc + d) * HW;
    float ax = 0.f, ay = 0.f, az = 0.f, aw = 0.f;

    if (w4 >= 4 && w4 <= Wc - 8) {
        // interior: wide taps 16B-aligned float4; narrow taps two 8B float2
#pragma unroll
        for (int s = 0; s < 9; ++s) {
            const int iy = s / 3, ix = s % 3;
            const float4 cw = *reinterpret_cast<const float4*>(
                sp + y2[iy] * Wc + w4 + (ix - 1) * 4);
            const float* np = sp + y1[iy] * Wc + w4 + (ix - 1) * 2;
            const float2 n0 = *reinterpret_cast<const float2*>(np);
            const float2 n1 = *reinterpret_cast<const float2*>(np + 2);
            const float4 ow = off4[s];
            const float4 on = off4[s + 9];
            ax = fmaf(on.x, n0.x, fmaf(ow.x, cw.x, ax));
            ay = fmaf(on.y, n0.y, fmaf(ow.y, cw.y, ay));
            az = fmaf(on.z, n1.x, fmaf(ow.z, cw.z, az));
            aw = fmaf(on.w, n1.y, fmaf(ow.w, cw.w, aw));
        }
    } else {
        // edge quad (w4==0 or w4==Wc-4): scalar gathers with x-reflect
        float acc[4] = {0.f, 0.f, 0.f, 0.f};
#pragma unroll
        for (int j = 0; j < 4; ++j) {
            const int w = w4 + j;
            float a = 0.f;
#pragma unroll
            for (int s = 0; s < 9; ++s) {
                const int iy = s / 3, ix = s % 3;
                int x1c = w + (ix - 1) * 2; x1c = x1c < 0 ? -x1c : (x1c >= Wc ? 2 * Wc - 2 - x1c : x1c);
                int x2c = w + (ix - 1) * 4; x2c = x2c < 0 ? -x2c : (x2c >= Wc ? 2 * Wc - 2 - x2c : x2c);
                const float on = j == 0 ? off4[s + 9].x : j == 1 ? off4[s + 9].y : j == 2 ? off4[s + 9].z : off4[s + 9].w;
                const float ow = j == 0 ? off4[s].x     : j == 1 ? off4[s].y     : j == 2 ? off4[s].z     : off4[s].w;
                a = fmaf(on, sp[y1[iy] * Wc + x1c], fmaf(ow, sp[y2[iy] * Wc + x2c], a));
            }
            acc[j] = a;
        }
        ax = acc[0]; ay = acc[1]; az = acc[2]; aw = acc[3];
    }

    float4 o4;
    o4.x = ax * wt4.x;
    o4.y = ay * wt4.y;
    o4.z = az * wt4.z;
    o4.w = aw * wt4.w;
    float* outb = out + (size_t)(b * Dc + d) * HW;
    *reinterpret_cast<float4*>(outb + hw4) = o4;
}

extern "C" void kernel_launch(void* const* d_in, const int* in_sizes, int n_in,
                              void* d_out, int out_size, void* d_ws, size_t ws_size,
                              hipStream_t stream)
{
    const float* x1     = (const float*)d_in[0];
    const float* offset = (const float*)d_in[1];
    const float* weight = (const float*)d_in[2];
    const float* w0     = (const float*)d_in[3];
    const float* s0     = (const float*)d_in[4];
    const float* b0     = (const float*)d_in[5];
    const float* w1     = (const float*)d_in[6];
    const float* s1     = (const float*)d_in[7];
    const float* b1     = (const float*)d_in[8];
    const float* wsim   = (const float*)d_in[9];
    const float* bsim   = (const float*)d_in[10];
    float* out = (float*)d_out;
    float* sim = (float*)d_ws;   // B*D*H*W floats = 5.25 MB scratch

    // 655360 point-pairs / 256 = 2560 blocks (exact)
    mlp_kernel<<<2560, 256, 0, stream>>>(x1, w0, s0, b0, w1, s1, b1, wsim, bsim, sim);
    // 327680 output-quads / 256 = 1280 blocks (exact)
    agg_kernel<<<1280, 256, 0, stream>>>(sim, offset, weight, out);
}

// Round 12
// 110.201 us; speedup vs baseline: 1.0491x; 1.0381x over previous
//
#include <hip/hip_runtime.h>

#define Gc 8
#define Dc 32
#define Hc 128
#define Wc 160
#define HW (Hc * Wc)         // 20480
#define DHW (Dc * HW)        // 655360

// ---------------------------------------------------------------------------
// Kernel A: per-point MLP 8 -> 16 -> 8 -> 1 (BN folded into LDS weights).
// One thread = TWO w-points (float2). Straight-line body (no loops: rounds
// 1-5 proved loops invite pipelining -> 208+ VGPR or spill; caps 84/64/128
// all spilled). ~60 VGPR -> 8 waves/SIMD. UNCHANGED from round 11.
// ---------------------------------------------------------------------------
__global__ __launch_bounds__(256) void mlp_kernel(
    const float* __restrict__ x1,
    const float* __restrict__ w0, const float* __restrict__ s0, const float* __restrict__ b0,
    const float* __restrict__ w1, const float* __restrict__ s1, const float* __restrict__ b1,
    const float* __restrict__ wsim, const float* __restrict__ bsim,
    float* __restrict__ sim)
{
    __shared__ float smw[289];
    const int tid = threadIdx.x;
    for (int i = tid; i < 289; i += 256) {
        float v;
        if (i < 128)      v = w0[i] * s0[i >> 3];                 // w0f[o][g]
        else if (i < 144) v = b0[i - 128];
        else if (i < 272) v = w1[i - 144] * s1[(i - 144) >> 4];   // w1f[c][o]
        else if (i < 280) v = b1[i - 272];
        else if (i < 288) v = wsim[i - 280];
        else              v = bsim[0];
        smw[i] = v;
    }
    __syncthreads();
    const float* sw0 = smw;
    const float* sb0 = smw + 128;
    const float* sw1 = smw + 144;
    const float* sb1 = smw + 272;
    const float* sws = smw + 280;
    const float  sbs = smw[288];

    const int t   = blockIdx.x * 256 + tid;   // 0 .. 655359 (exact grid)
    const int p   = t << 1;                   // base point over (b,d,h,w)
    const int b   = p / DHW;
    const int dhw = p - b * DHW;
    const float* xb = x1 + (size_t)b * (Gc * DHW) + dhw;

    float2 xv[Gc];
#pragma unroll
    for (int g = 0; g < Gc; ++g)
        xv[g] = *reinterpret_cast<const float2*>(xb + g * DHW);

    float2 acc1[8];
#pragma unroll
    for (int c = 0; c < 8; ++c) {
        const float bb = sb1[c];
        acc1[c].x = bb; acc1[c].y = bb;
    }

#pragma unroll
    for (int o = 0; o < 16; ++o) {
        float ax = sb0[o], ay = ax;
#pragma unroll
        for (int g = 0; g < Gc; ++g) {
            const float wv = sw0[o * Gc + g];
            ax = fmaf(wv, xv[g].x, ax);
            ay = fmaf(wv, xv[g].y, ay);
        }
        ax = fmaxf(ax, 0.f);
        ay = fmaxf(ay, 0.f);
#pragma unroll
        for (int c = 0; c < 8; ++c) {
            const float wv = sw1[c * 16 + o];
            acc1[c].x = fmaf(wv, ax, acc1[c].x);
            acc1[c].y = fmaf(wv, ay, acc1[c].y);
        }
    }

    float sx = sbs, sy = sbs;
#pragma unroll
    for (int c = 0; c < 8; ++c) {
        const float ws = sws[c];
        sx = fmaf(ws, fmaxf(acc1[c].x, 0.f), sx);
        sy = fmaf(ws, fmaxf(acc1[c].y, 0.f), sy);
    }

    float2 r; r.x = sx; r.y = sy;
    *reinterpret_cast<float2*>(sim + p) = r;
}

// ---------------------------------------------------------------------------
// Kernel B: 9-neighbor aggregation. Same body as the proven round-9/11
// version; ONLY the thread decode order changed: (w4, d, h, b) instead of
// (w4, h, d, b). A 256-thread block now spans ~6-7 consecutive d at a FIXED
// h, so the d-independent offset row (19 x 640B = 12 KB) and the 5 distinct
// sim rows per d-plane fit the 32 KB L1 -> offset loads become L1 hits
// instead of 32x-repeated L2 fetches (~100 MB L2 traffic -> ~16 MB).
// Wave coalescing preserved: lanes 0-39 sweep the full w row; lanes 40-63
// re-read the same offset lines (coalescer broadcast) + a second contiguous
// sim segment for d+1.
// ---------------------------------------------------------------------------
__global__ __launch_bounds__(256) void agg_kernel(
    const float* __restrict__ sim, const float* __restrict__ offset,
    const float* __restrict__ weight, float* __restrict__ out)
{
    const int l  = blockIdx.x * 256 + threadIdx.x;  // 0 .. 327679 (exact)
    const int q  = l % (Wc / 4);
    const int w4 = q * 4;
    int r = l / (Wc / 4);
    const int d  = r & 31;                          // d fastest after w4
    r >>= 5;
    const int h  = r % Hc;
    const int b  = r / Hc;                          // 0..1
    const int hw4 = h * Wc + w4;

    const float* offb = offset + (size_t)b * 18 * HW;
    float4 off4[18];
#pragma unroll
    for (int s = 0; s < 18; ++s)
        off4[s] = *reinterpret_cast<const float4*>(offb + s * HW + hw4);
    float4 wt4 = *reinterpret_cast<const float4*>(weight + (size_t)b * HW + hw4);
    wt4.x *= 0.5f; wt4.y *= 0.5f; wt4.z *= 0.5f; wt4.w *= 0.5f;

    int y1[3], y2[3];
#pragma unroll
    for (int iy = 0; iy < 3; ++iy) {
        int a1 = h + (iy - 1) * 2; y1[iy] = a1 < 0 ? -a1 : (a1 >= Hc ? 2 * Hc - 2 - a1 : a1);
        int a2 = h + (iy - 1) * 4; y2[iy] = a2 < 0 ? -a2 : (a2 >= Hc ? 2 * Hc - 2 - a2 : a2);
    }

    const float* sp = sim + (size_t)(b * Dc + d) * HW;
    float ax = 0.f, ay = 0.f, az = 0.f, aw = 0.f;

    if (w4 >= 4 && w4 <= Wc - 8) {
        // interior: wide taps 16B-aligned float4; narrow taps two 8B float2
#pragma unroll
        for (int s = 0; s < 9; ++s) {
            const int iy = s / 3, ix = s % 3;
            const float4 cw = *reinterpret_cast<const float4*>(
                sp + y2[iy] * Wc + w4 + (ix - 1) * 4);
            const float* np = sp + y1[iy] * Wc + w4 + (ix - 1) * 2;
            const float2 n0 = *reinterpret_cast<const float2*>(np);
            const float2 n1 = *reinterpret_cast<const float2*>(np + 2);
            const float4 ow = off4[s];
            const float4 on = off4[s + 9];
            ax = fmaf(on.x, n0.x, fmaf(ow.x, cw.x, ax));
            ay = fmaf(on.y, n0.y, fmaf(ow.y, cw.y, ay));
            az = fmaf(on.z, n1.x, fmaf(ow.z, cw.z, az));
            aw = fmaf(on.w, n1.y, fmaf(ow.w, cw.w, aw));
        }
    } else {
        // edge quad (w4==0 or w4==Wc-4): scalar gathers with x-reflect
        float acc[4] = {0.f, 0.f, 0.f, 0.f};
#pragma unroll
        for (int j = 0; j < 4; ++j) {
            const int w = w4 + j;
            float a = 0.f;
#pragma unroll
            for (int s = 0; s < 9; ++s) {
                const int iy = s / 3, ix = s % 3;
                int x1c = w + (ix - 1) * 2; x1c = x1c < 0 ? -x1c : (x1c >= Wc ? 2 * Wc - 2 - x1c : x1c);
                int x2c = w + (ix - 1) * 4; x2c = x2c < 0 ? -x2c : (x2c >= Wc ? 2 * Wc - 2 - x2c : x2c);
                const float on = j == 0 ? off4[s + 9].x : j == 1 ? off4[s + 9].y : j == 2 ? off4[s + 9].z : off4[s + 9].w;
                const float ow = j == 0 ? off4[s].x     : j == 1 ? off4[s].y     : j == 2 ? off4[s].z     : off4[s].w;
                a = fmaf(on, sp[y1[iy] * Wc + x1c], fmaf(ow, sp[y2[iy] * Wc + x2c], a));
            }
            acc[j] = a;
        }
        ax = acc[0]; ay = acc[1]; az = acc[2]; aw = acc[3];
    }

    float4 o4;
    o4.x = ax * wt4.x;
    o4.y = ay * wt4.y;
    o4.z = az * wt4.z;
    o4.w = aw * wt4.w;
    float* outb = out + (size_t)(b * Dc + d) * HW;
    *reinterpret_cast<float4*>(outb + hw4) = o4;
}

extern "C" void kernel_launch(void* const* d_in, const int* in_sizes, int n_in,
                              void* d_out, int out_size, void* d_ws, size_t ws_size,
                              hipStream_t stream)
{
    const float* x1     = (const float*)d_in[0];
    const float* offset = (const float*)d_in[1];
    const float* weight = (const float*)d_in[2];
    const float* w0     = (const float*)d_in[3];
    const float* s0     = (const float*)d_in[4];
    const float* b0     = (const float*)d_in[5];
    const float* w1     = (const float*)d_in[6];
    const float* s1     = (const float*)d_in[7];
    const float* b1     = (const float*)d_in[8];
    const float* wsim   = (const float*)d_in[9];
    const float* bsim   = (const float*)d_in[10];
    float* out = (float*)d_out;
    float* sim = (float*)d_ws;   // B*D*H*W floats = 5.25 MB scratch

    // 655360 point-pairs / 256 = 2560 blocks (exact)
    mlp_kernel<<<2560, 256, 0, stream>>>(x1, w0, s0, b0, w1, s1, b1, wsim, bsim, sim);
    // 327680 output-quads / 256 = 1280 blocks (exact)
    agg_kernel<<<1280, 256, 0, stream>>>(sim, offset, weight, out);
}